// Round 1
// 548.603 us; speedup vs baseline: 1.2345x; 1.2345x over previous
//
#include <hip/hip_runtime.h>

#define NN 200000
#define NE 600000
#define DD 128
#define GT 1563   // ceil(NN/128) gemm row tiles

constexpr float BN_EPS = 1e-5f;

typedef unsigned short u16;
typedef short bf16x8 __attribute__((ext_vector_type(8)));
typedef float f32x4  __attribute__((ext_vector_type(4)));

// ---------------- init / degree / stats ----------------

__global__ void k_zero(int* __restrict__ cnt, float* __restrict__ ssum, float* __restrict__ ssq) {
  int i = blockIdx.x*256 + threadIdx.x;
  if (i < NN) cnt[i] = 0;
  if (i < DD) { ssum[i] = 0.f; ssq[i] = 0.f; }
}

__global__ void k_count(const int* __restrict__ ei, int* __restrict__ cnt) {
  int e = blockIdx.x*256 + threadIdx.x;
  if (e < NE) atomicAdd(&cnt[ei[NE + e]], 1);
}

// column sums of prelu(x, a1): ssum[c], ssq[c]
__global__ void k_stats(const float* __restrict__ x, const float* __restrict__ a1p,
                        float* __restrict__ ssum, float* __restrict__ ssq) {
  __shared__ float s1[256], s2[256];
  int col  = threadIdx.x & 127;
  int half = threadIdx.x >> 7;
  float a1 = *a1p;
  float acc1 = 0.f, acc2 = 0.f;
  int stride = gridDim.x * 2;
  for (int r = blockIdx.x*2 + half; r < NN; r += stride) {
    float v = x[(size_t)r*DD + col];
    v = (v >= 0.f) ? v : a1*v;
    acc1 += v; acc2 += v*v;
  }
  s1[threadIdx.x] = acc1; s2[threadIdx.x] = acc2;
  __syncthreads();
  if (threadIdx.x < 128) {
    atomicAdd(&ssum[col], s1[threadIdx.x] + s1[threadIdx.x + 128]);
    atomicAdd(&ssq [col], s2[threadIdx.x] + s2[threadIdx.x + 128]);
  }
}

// BN params s,t and tw1[j] = sum_k t[k] * W1[k,j]   (single block, 128 threads)
__global__ void k_bn_tw1(const float* __restrict__ ssum, const float* __restrict__ ssq,
                         const float* __restrict__ gamma, const float* __restrict__ beta,
                         const float* __restrict__ W1,
                         float* __restrict__ sarr, float* __restrict__ tarr,
                         float* __restrict__ tw1) {
  __shared__ float ts[128];
  int j = threadIdx.x;
  float mean = ssum[j] * (1.f/NN);
  float var  = ssq[j] * (1.f/NN) - mean*mean;
  float s = gamma[j] * rsqrtf(var + BN_EPS);
  float t = beta[j] - mean*s;
  sarr[j] = s; tarr[j] = t; ts[j] = t;
  __syncthreads();
  float acc = 0.f;
  #pragma unroll 8
  for (int k = 0; k < 128; ++k) acc += ts[k] * W1[k*DD + j];
  tw1[j] = acc;
}

// W prep: Wt[j][k] = (s ? s[k] : 1) * W[k][j], split into bf16 hi/lo (truncation).
// 16384 elements, grid 64 x 256.
__global__ void k_wprep(const float* __restrict__ W, const float* __restrict__ s,
                        u16* __restrict__ hi, u16* __restrict__ lo) {
  int idx = blockIdx.x*256 + threadIdx.x;
  int j = idx >> 7, k = idx & 127;
  float v = W[(size_t)k*DD + j];
  if (s) v *= s[k];
  unsigned hb = __float_as_uint(v) & 0xffff0000u;
  float r = v - __uint_as_float(hb);           // exact residual
  hi[idx] = (u16)(hb >> 16);
  lo[idx] = (u16)(__float_as_uint(r) >> 16);
}

// ---------------- exclusive scan (3 pass) ----------------

__global__ void k_scan1(const int* __restrict__ cnt, int* __restrict__ rp, int* __restrict__ bsums) {
  __shared__ int sm[256];
  int tid = threadIdx.x;
  int base = blockIdx.x*1024 + tid*4;
  int4 v = make_int4(0,0,0,0);
  if (base + 3 < NN) v = *(const int4*)(cnt + base);
  else {
    if (base   < NN) v.x = cnt[base];
    if (base+1 < NN) v.y = cnt[base+1];
    if (base+2 < NN) v.z = cnt[base+2];
    if (base+3 < NN) v.w = cnt[base+3];
  }
  int p1 = v.x, p2 = p1 + v.y, p3 = p2 + v.z, tsum = p3 + v.w;
  sm[tid] = tsum; __syncthreads();
  for (int off = 1; off < 256; off <<= 1) {
    int t = (tid >= off) ? sm[tid - off] : 0; __syncthreads();
    sm[tid] += t; __syncthreads();
  }
  int inc = sm[tid];
  int excl = inc - tsum;
  if (base   < NN) rp[base]   = excl;
  if (base+1 < NN) rp[base+1] = excl + p1;
  if (base+2 < NN) rp[base+2] = excl + p2;
  if (base+3 < NN) rp[base+3] = excl + p3;
  if (tid == 255) bsums[blockIdx.x] = inc;
}

__global__ void k_scan2(int* __restrict__ bsums, int nb) {
  __shared__ int sm[256];
  int tid = threadIdx.x;
  int v = (tid < nb) ? bsums[tid] : 0;
  sm[tid] = v; __syncthreads();
  for (int off = 1; off < 256; off <<= 1) {
    int t = (tid >= off) ? sm[tid - off] : 0; __syncthreads();
    sm[tid] += t; __syncthreads();
  }
  if (tid < nb) bsums[tid] = sm[tid] - v;   // exclusive
}

// fused: finalize row pointers + cur + dinv
__global__ void k_scan3(int* __restrict__ rp, const int* __restrict__ bsums,
                        int* __restrict__ cur, const int* __restrict__ cnt,
                        float* __restrict__ dinv) {
  int i = blockIdx.x*256 + threadIdx.x;
  if (i < NN) {
    int val = rp[i] + bsums[i >> 10];
    rp[i] = val; cur[i] = val;
    dinv[i] = rsqrtf((float)(cnt[i] + 1));
  }
  if (i == 0) rp[NN] = NE;
}

__global__ void k_fill(const int* __restrict__ ei, const float* __restrict__ dinv,
                       int* __restrict__ cur, int2* __restrict__ pairs) {
  int e = blockIdx.x*256 + threadIdx.x;
  if (e < NE) {
    int s = ei[e], d = ei[NE + e];
    int pos = atomicAdd(&cur[d], 1);
    float cf = dinv[s] * dinv[d];
    pairs[pos] = make_int2(s, __float_as_int(cf));
  }
}

// ---------------- GEMM: C[N,128] = prelu(A)[N,128] @ W'[128,128] (+ row add) ----------------
// MFMA bf16x3 split-precision: A = Ah+Al, W' = Wh+Wl (pre-split, transposed, BN scale
// folded into W1). acc += Ah*Wh + Ah*Wl + Al*Wh  -> ~fp32 accuracy at MFMA rate.
// Block: 256 thr = 4 waves, 128 rows x 128 cols. Wave: 32 rows (2 strips of 16), 8 col tiles.
// Wt hi/lo staged in LDS [128][136] (272B row stride: 16B-aligned, min 2-way bank aliasing).
// A streamed global->reg (2x float4 per strip per K-chunk), split on the fly.
// Memory-bound target: ~205 MB at ~6 TB/s => ~35-45 us.

template<bool FUSE, bool ADDROW>
__global__ __launch_bounds__(256)
void k_gemm(const float* __restrict__ A,
            const u16* __restrict__ wt_hi, const u16* __restrict__ wt_lo,
            float* __restrict__ C,
            const float* __restrict__ tw1, const float* __restrict__ a1p)
{
  __shared__ u16 Bh[128][136];
  __shared__ u16 Bl[128][136];
  const int tid = threadIdx.x;

  // stage Wt hi/lo: 2048 16B chunks each, 8 per thread
  #pragma unroll
  for (int i = 0; i < 8; ++i) {
    int c = tid + i*256;
    int row = c >> 4, slot = c & 15;
    *(uint4*)&Bh[row][slot*8] = ((const uint4*)wt_hi)[c];
    *(uint4*)&Bl[row][slot*8] = ((const uint4*)wt_lo)[c];
  }

  float a1v = 0.f;
  if constexpr (FUSE) a1v = *a1p;

  const int lane = tid & 63;
  const int wv   = tid >> 6;            // wave 0..3
  const int lr   = lane & 15;           // A row within strip / C col within tile
  const int lk   = lane >> 4;           // k sub-block 0..3
  const int r0   = blockIdx.x*128 + wv*32;

  f32x4 acc[2][8];
  #pragma unroll
  for (int s = 0; s < 2; ++s)
    #pragma unroll
    for (int j = 0; j < 8; ++j) acc[s][j] = (f32x4){0.f,0.f,0.f,0.f};

  __syncthreads();

  #pragma unroll
  for (int kc = 0; kc < 4; ++kc) {
    bf16x8 ah[2], al[2];
    #pragma unroll
    for (int s = 0; s < 2; ++s) {
      int r = r0 + s*16 + lr; if (r >= NN) r = NN-1;
      const float* ap = A + (size_t)r*DD + kc*32 + lk*8;
      float4 v0 = *(const float4*)ap;
      float4 v1 = *(const float4*)(ap + 4);
      float vv[8] = {v0.x,v0.y,v0.z,v0.w,v1.x,v1.y,v1.z,v1.w};
      #pragma unroll
      for (int e = 0; e < 8; ++e) {
        float v = vv[e];
        if constexpr (FUSE) v = (v >= 0.f) ? v : a1v*v;
        unsigned hb = __float_as_uint(v) & 0xffff0000u;
        float rres = v - __uint_as_float(hb);    // exact
        ah[s][e] = (short)(hb >> 16);
        al[s][e] = (short)(__float_as_uint(rres) >> 16);
      }
    }
    #pragma unroll
    for (int j = 0; j < 8; ++j) {
      int wrow = j*16 + lr;
      bf16x8 bh = *(const bf16x8*)&Bh[wrow][kc*32 + lk*8];
      bf16x8 bl = *(const bf16x8*)&Bl[wrow][kc*32 + lk*8];
      #pragma unroll
      for (int s = 0; s < 2; ++s) {
        acc[s][j] = __builtin_amdgcn_mfma_f32_16x16x32_bf16(ah[s], bh, acc[s][j], 0, 0, 0);
        acc[s][j] = __builtin_amdgcn_mfma_f32_16x16x32_bf16(ah[s], bl, acc[s][j], 0, 0, 0);
        acc[s][j] = __builtin_amdgcn_mfma_f32_16x16x32_bf16(al[s], bh, acc[s][j], 0, 0, 0);
      }
    }
  }

  float tw[8];
  #pragma unroll
  for (int j = 0; j < 8; ++j) tw[j] = 0.f;
  if constexpr (ADDROW) {
    #pragma unroll
    for (int j = 0; j < 8; ++j) tw[j] = tw1[j*16 + lr];
  }

  // C/D layout (m89): col = lane&15, row = (lane>>4)*4 + reg
  #pragma unroll
  for (int s = 0; s < 2; ++s) {
    #pragma unroll
    for (int g = 0; g < 4; ++g) {
      int row = r0 + s*16 + lk*4 + g;
      if (row < NN) {
        float* cp = C + (size_t)row*DD + lr;
        #pragma unroll
        for (int j = 0; j < 8; ++j) cp[j*16] = acc[s][j][g] + tw[j];
      }
    }
  }
}

// ---------------- aggregation: one wave per node, edge-unrolled gathers ----------------

template<bool PRELU>
__global__ __launch_bounds__(256)
void k_agg(const float* __restrict__ h, const int* __restrict__ rp,
           const int2* __restrict__ pairs, const float* __restrict__ dinv,
           const float* __restrict__ bias, const float* __restrict__ a2p,
           float* __restrict__ out)
{
  int wave = threadIdx.x >> 6;
  int lane = threadIdx.x & 63;
  int node = blockIdx.x*4 + wave;
  if (node >= NN) return;
  const float2* h2 = (const float2*)h;
  float2* o2 = (float2*)out;
  int beg = rp[node], end = rp[node+1];
  float di = dinv[node];
  float2 self = h2[(size_t)node*64 + lane];
  float2 b = ((const float2*)bias)[lane];
  float a2 = 1.f;
  if constexpr (PRELU) a2 = *a2p;
  float sc = di*di;
  float ax = sc*self.x + b.x, ay = sc*self.y + b.y;
  int e = beg;
  for (; e + 4 <= end; e += 4) {
    int2 p0 = pairs[e], p1 = pairs[e+1], p2 = pairs[e+2], p3 = pairs[e+3];
    float2 g0 = h2[(size_t)p0.x*64 + lane];
    float2 g1 = h2[(size_t)p1.x*64 + lane];
    float2 g2 = h2[(size_t)p2.x*64 + lane];
    float2 g3 = h2[(size_t)p3.x*64 + lane];
    float c0 = __int_as_float(p0.y), c1 = __int_as_float(p1.y);
    float c2 = __int_as_float(p2.y), c3 = __int_as_float(p3.y);
    ax += c0*g0.x + c1*g1.x + c2*g2.x + c3*g3.x;
    ay += c0*g0.y + c1*g1.y + c2*g2.y + c3*g3.y;
  }
  if (e + 2 <= end) {
    int2 p0 = pairs[e], p1 = pairs[e+1];
    float2 g0 = h2[(size_t)p0.x*64 + lane];
    float2 g1 = h2[(size_t)p1.x*64 + lane];
    float c0 = __int_as_float(p0.y), c1 = __int_as_float(p1.y);
    ax += c0*g0.x + c1*g1.x;
    ay += c0*g0.y + c1*g1.y;
    e += 2;
  }
  if (e < end) {
    int2 p0 = pairs[e];
    float2 g0 = h2[(size_t)p0.x*64 + lane];
    float c0 = __int_as_float(p0.y);
    ax += c0*g0.x; ay += c0*g0.y;
  }
  if constexpr (PRELU) {
    ax = (ax >= 0.f) ? ax : a2*ax;
    ay = (ay >= 0.f) ? ay : a2*ay;
  }
  o2[(size_t)node*64 + lane] = make_float2(ax, ay);
}

// ---------------- launch ----------------

extern "C" void kernel_launch(void* const* d_in, const int* in_sizes, int n_in,
                              void* d_out, int out_size, void* d_ws, size_t ws_size,
                              hipStream_t stream) {
  const float* x     = (const float*)d_in[0];
  const int*   ei    = (const int*)  d_in[1];
  const float* a1    = (const float*)d_in[2];
  const float* gamma = (const float*)d_in[3];
  const float* beta  = (const float*)d_in[4];
  const float* W1    = (const float*)d_in[5];
  const float* b1    = (const float*)d_in[6];
  const float* a2    = (const float*)d_in[7];
  const float* W2    = (const float*)d_in[8];
  const float* b2    = (const float*)d_in[9];
  float* out = (float*)d_out;

  char* w = (char*)d_ws;
  auto alloc = [&](size_t bytes) { char* p = w; w += (bytes + 255) & ~(size_t)255; return p; };
  float* hbuf  = (float*)alloc((size_t)NN*DD*4);   // 102.4 MB
  float* dinv  = (float*)alloc((size_t)NN*4);
  int*   cnt   = (int*)  alloc((size_t)NN*4);
  int*   rp    = (int*)  alloc((size_t)(NN+1)*4);
  int*   cur   = (int*)  alloc((size_t)NN*4);
  int2*  pairs = (int2*) alloc((size_t)NE*8);
  int*   bsums = (int*)  alloc(256*4);
  float* ssum  = (float*)alloc(128*4);
  float* ssq   = (float*)alloc(128*4);
  float* sarr  = (float*)alloc(128*4);
  float* tarr  = (float*)alloc(128*4);
  float* tw1   = (float*)alloc(128*4);
  u16*   w1h   = (u16*)  alloc(128*128*2);
  u16*   w1l   = (u16*)  alloc(128*128*2);
  u16*   w2h   = (u16*)  alloc(128*128*2);
  u16*   w2l   = (u16*)  alloc(128*128*2);

  const int nblkN = (NN + 255)/256;
  const int nblkE = (NE + 255)/256;

  k_zero  <<<nblkN, 256, 0, stream>>>(cnt, ssum, ssq);
  k_count <<<nblkE, 256, 0, stream>>>(ei, cnt);
  k_stats <<<768,   256, 0, stream>>>(x, a1, ssum, ssq);
  k_bn_tw1<<<1,     128, 0, stream>>>(ssum, ssq, gamma, beta, W1, sarr, tarr, tw1);
  k_wprep <<<64,    256, 0, stream>>>(W2, nullptr, w2h, w2l);
  k_wprep <<<64,    256, 0, stream>>>(W1, sarr,    w1h, w1l);
  k_scan1 <<<196,   256, 0, stream>>>(cnt, rp, bsums);
  k_scan2 <<<1,     256, 0, stream>>>(bsums, 196);
  k_scan3 <<<nblkN, 256, 0, stream>>>(rp, bsums, cur, cnt, dinv);
  k_fill  <<<nblkE, 256, 0, stream>>>(ei, dinv, cur, pairs);

  k_gemm<true,  true ><<<GT, 256, 0, stream>>>(x,   w1h, w1l, hbuf, tw1, a1);
  k_agg <true >        <<<NN/4, 256, 0, stream>>>(hbuf, rp, pairs, dinv, b1, a2, out);
  k_gemm<false, false><<<GT, 256, 0, stream>>>(out, w2h, w2l, hbuf, nullptr, nullptr);
  k_agg <false>        <<<NN/4, 256, 0, stream>>>(hbuf, rp, pairs, dinv, b2, nullptr, out);
}

// Round 2
// 513.547 us; speedup vs baseline: 1.3188x; 1.0683x over previous
//
#include <hip/hip_runtime.h>

#define NN 200000
#define NE 600000
#define DD 128
#define GT 1563   // ceil(NN/128) gemm row tiles

constexpr float BN_EPS = 1e-5f;

typedef unsigned short u16;
typedef short bf16x8 __attribute__((ext_vector_type(8)));
typedef float f32x4  __attribute__((ext_vector_type(4)));

// ---------------- init / degree / stats ----------------

__global__ void k_zero(int* __restrict__ cnt, float* __restrict__ ssum, float* __restrict__ ssq) {
  int i = blockIdx.x*256 + threadIdx.x;
  if (i < NN) cnt[i] = 0;
  if (i < DD) { ssum[i] = 0.f; ssq[i] = 0.f; }
}

__global__ void k_count(const int* __restrict__ ei, int* __restrict__ cnt) {
  int e = blockIdx.x*256 + threadIdx.x;
  if (e < NE) atomicAdd(&cnt[ei[NE + e]], 1);
}

// column sums of prelu(x, a1): ssum[c], ssq[c]
// float4 per lane (16B), 8 row-groups/block, LDS reduce, 1 atomic/col/block.
__global__ void k_stats(const float* __restrict__ x, const float* __restrict__ a1p,
                        float* __restrict__ ssum, float* __restrict__ ssq) {
  __shared__ float s1[8][128], s2[8][128];
  const int c4 = (threadIdx.x & 31) * 4;
  const int rg = threadIdx.x >> 5;
  float a1 = *a1p;
  float acc1[4] = {0.f,0.f,0.f,0.f}, acc2[4] = {0.f,0.f,0.f,0.f};
  const int stride = gridDim.x * 8;
  for (int r = blockIdx.x*8 + rg; r < NN; r += stride) {
    float4 v = *(const float4*)(x + (size_t)r*DD + c4);
    float vv[4] = {v.x, v.y, v.z, v.w};
    #pragma unroll
    for (int i = 0; i < 4; ++i) {
      float u = vv[i];
      u = (u >= 0.f) ? u : a1*u;
      acc1[i] += u; acc2[i] += u*u;
    }
  }
  *(float4*)&s1[rg][c4] = make_float4(acc1[0], acc1[1], acc1[2], acc1[3]);
  *(float4*)&s2[rg][c4] = make_float4(acc2[0], acc2[1], acc2[2], acc2[3]);
  __syncthreads();
  if (threadIdx.x < 128) {
    int col = threadIdx.x;
    float t1 = 0.f, t2 = 0.f;
    #pragma unroll
    for (int g = 0; g < 8; ++g) { t1 += s1[g][col]; t2 += s2[g][col]; }
    atomicAdd(&ssum[col], t1);
    atomicAdd(&ssq [col], t2);
  }
}

// BN params s,t and tw1[j] = sum_k t[k] * W1[k,j]   (single block, 128 threads)
__global__ void k_bn_tw1(const float* __restrict__ ssum, const float* __restrict__ ssq,
                         const float* __restrict__ gamma, const float* __restrict__ beta,
                         const float* __restrict__ W1,
                         float* __restrict__ sarr, float* __restrict__ tarr,
                         float* __restrict__ tw1) {
  __shared__ float ts[128];
  int j = threadIdx.x;
  float mean = ssum[j] * (1.f/NN);
  float var  = ssq[j] * (1.f/NN) - mean*mean;
  float s = gamma[j] * rsqrtf(var + BN_EPS);
  float t = beta[j] - mean*s;
  sarr[j] = s; tarr[j] = t; ts[j] = t;
  __syncthreads();
  float acc = 0.f;
  #pragma unroll 8
  for (int k = 0; k < 128; ++k) acc += ts[k] * W1[k*DD + j];
  tw1[j] = acc;
}

// W prep: Wt[j][k] = (s ? s[k] : 1) * W[k][j], split into bf16 hi/lo (truncation).
// 16384 elements, grid 64 x 256.
__global__ void k_wprep(const float* __restrict__ W, const float* __restrict__ s,
                        u16* __restrict__ hi, u16* __restrict__ lo) {
  int idx = blockIdx.x*256 + threadIdx.x;
  int j = idx >> 7, k = idx & 127;
  float v = W[(size_t)k*DD + j];
  if (s) v *= s[k];
  unsigned hb = __float_as_uint(v) & 0xffff0000u;
  float r = v - __uint_as_float(hb);           // exact residual
  hi[idx] = (u16)(hb >> 16);
  lo[idx] = (u16)(__float_as_uint(r) >> 16);
}

// ---------------- exclusive scan (3 pass) ----------------

__global__ void k_scan1(const int* __restrict__ cnt, int* __restrict__ rp, int* __restrict__ bsums) {
  __shared__ int sm[256];
  int tid = threadIdx.x;
  int base = blockIdx.x*1024 + tid*4;
  int4 v = make_int4(0,0,0,0);
  if (base + 3 < NN) v = *(const int4*)(cnt + base);
  else {
    if (base   < NN) v.x = cnt[base];
    if (base+1 < NN) v.y = cnt[base+1];
    if (base+2 < NN) v.z = cnt[base+2];
    if (base+3 < NN) v.w = cnt[base+3];
  }
  int p1 = v.x, p2 = p1 + v.y, p3 = p2 + v.z, tsum = p3 + v.w;
  sm[tid] = tsum; __syncthreads();
  for (int off = 1; off < 256; off <<= 1) {
    int t = (tid >= off) ? sm[tid - off] : 0; __syncthreads();
    sm[tid] += t; __syncthreads();
  }
  int inc = sm[tid];
  int excl = inc - tsum;
  if (base   < NN) rp[base]   = excl;
  if (base+1 < NN) rp[base+1] = excl + p1;
  if (base+2 < NN) rp[base+2] = excl + p2;
  if (base+3 < NN) rp[base+3] = excl + p3;
  if (tid == 255) bsums[blockIdx.x] = inc;
}

__global__ void k_scan2(int* __restrict__ bsums, int nb) {
  __shared__ int sm[256];
  int tid = threadIdx.x;
  int v = (tid < nb) ? bsums[tid] : 0;
  sm[tid] = v; __syncthreads();
  for (int off = 1; off < 256; off <<= 1) {
    int t = (tid >= off) ? sm[tid - off] : 0; __syncthreads();
    sm[tid] += t; __syncthreads();
  }
  if (tid < nb) bsums[tid] = sm[tid] - v;   // exclusive
}

// fused: finalize row pointers + cur + dinv
__global__ void k_scan3(int* __restrict__ rp, const int* __restrict__ bsums,
                        int* __restrict__ cur, const int* __restrict__ cnt,
                        float* __restrict__ dinv) {
  int i = blockIdx.x*256 + threadIdx.x;
  if (i < NN) {
    int val = rp[i] + bsums[i >> 10];
    rp[i] = val; cur[i] = val;
    dinv[i] = rsqrtf((float)(cnt[i] + 1));
  }
  if (i == 0) rp[NN] = NE;
}

__global__ void k_fill(const int* __restrict__ ei, const float* __restrict__ dinv,
                       int* __restrict__ cur, int2* __restrict__ pairs) {
  int e = blockIdx.x*256 + threadIdx.x;
  if (e < NE) {
    int s = ei[e], d = ei[NE + e];
    int pos = atomicAdd(&cur[d], 1);
    float cf = dinv[s] * dinv[d];
    pairs[pos] = make_int2(s, __float_as_int(cf));
  }
}

// ---------------- GEMM: C[N,128] = prelu(A)[N,128] @ W'[128,128] (+ row add) ----------------
// MFMA bf16x3 split-precision: A = Ah+Al, W' = Wh+Wl (pre-split, transposed, BN scale
// folded into W1). acc += Ah*Wh + Ah*Wl + Al*Wh  -> ~fp32 accuracy at MFMA rate.
// Block: 256 thr = 4 waves, 128 rows x 128 cols. Wave: 32 rows (2 strips of 16), 8 col tiles.
// Wt hi/lo staged in LDS [128][136] (272B row stride: 16B-aligned, min 2-way bank aliasing).
// A streamed global->reg (2x float4 per strip per K-chunk), split on the fly.

template<bool FUSE, bool ADDROW>
__global__ __launch_bounds__(256)
void k_gemm(const float* __restrict__ A,
            const u16* __restrict__ wt_hi, const u16* __restrict__ wt_lo,
            float* __restrict__ C,
            const float* __restrict__ tw1, const float* __restrict__ a1p)
{
  __shared__ u16 Bh[128][136];
  __shared__ u16 Bl[128][136];
  const int tid = threadIdx.x;

  // stage Wt hi/lo: 2048 16B chunks each, 8 per thread
  #pragma unroll
  for (int i = 0; i < 8; ++i) {
    int c = tid + i*256;
    int row = c >> 4, slot = c & 15;
    *(uint4*)&Bh[row][slot*8] = ((const uint4*)wt_hi)[c];
    *(uint4*)&Bl[row][slot*8] = ((const uint4*)wt_lo)[c];
  }

  float a1v = 0.f;
  if constexpr (FUSE) a1v = *a1p;

  const int lane = tid & 63;
  const int wv   = tid >> 6;            // wave 0..3
  const int lr   = lane & 15;           // A row within strip / C col within tile
  const int lk   = lane >> 4;           // k sub-block 0..3
  const int r0   = blockIdx.x*128 + wv*32;

  f32x4 acc[2][8];
  #pragma unroll
  for (int s = 0; s < 2; ++s)
    #pragma unroll
    for (int j = 0; j < 8; ++j) acc[s][j] = (f32x4){0.f,0.f,0.f,0.f};

  __syncthreads();

  #pragma unroll
  for (int kc = 0; kc < 4; ++kc) {
    bf16x8 ah[2], al[2];
    #pragma unroll
    for (int s = 0; s < 2; ++s) {
      int r = r0 + s*16 + lr; if (r >= NN) r = NN-1;
      const float* ap = A + (size_t)r*DD + kc*32 + lk*8;
      float4 v0 = *(const float4*)ap;
      float4 v1 = *(const float4*)(ap + 4);
      float vv[8] = {v0.x,v0.y,v0.z,v0.w,v1.x,v1.y,v1.z,v1.w};
      #pragma unroll
      for (int e = 0; e < 8; ++e) {
        float v = vv[e];
        if constexpr (FUSE) v = (v >= 0.f) ? v : a1v*v;
        unsigned hb = __float_as_uint(v) & 0xffff0000u;
        float rres = v - __uint_as_float(hb);    // exact
        ah[s][e] = (short)(hb >> 16);
        al[s][e] = (short)(__float_as_uint(rres) >> 16);
      }
    }
    #pragma unroll
    for (int j = 0; j < 8; ++j) {
      int wrow = j*16 + lr;
      bf16x8 bh = *(const bf16x8*)&Bh[wrow][kc*32 + lk*8];
      bf16x8 bl = *(const bf16x8*)&Bl[wrow][kc*32 + lk*8];
      #pragma unroll
      for (int s = 0; s < 2; ++s) {
        acc[s][j] = __builtin_amdgcn_mfma_f32_16x16x32_bf16(ah[s], bh, acc[s][j], 0, 0, 0);
        acc[s][j] = __builtin_amdgcn_mfma_f32_16x16x32_bf16(ah[s], bl, acc[s][j], 0, 0, 0);
        acc[s][j] = __builtin_amdgcn_mfma_f32_16x16x32_bf16(al[s], bh, acc[s][j], 0, 0, 0);
      }
    }
  }

  float tw[8];
  #pragma unroll
  for (int j = 0; j < 8; ++j) tw[j] = 0.f;
  if constexpr (ADDROW) {
    #pragma unroll
    for (int j = 0; j < 8; ++j) tw[j] = tw1[j*16 + lr];
  }

  // C/D layout (m89): col = lane&15, row = (lane>>4)*4 + reg
  #pragma unroll
  for (int s = 0; s < 2; ++s) {
    #pragma unroll
    for (int g = 0; g < 4; ++g) {
      int row = r0 + s*16 + lk*4 + g;
      if (row < NN) {
        float* cp = C + (size_t)row*DD + lr;
        #pragma unroll
        for (int j = 0; j < 8; ++j) cp[j*16] = acc[s][j][g] + tw[j];
      }
    }
  }
}

// ---------------- aggregation: one wave per node, edge-unrolled gathers ----------------

template<bool PRELU>
__global__ __launch_bounds__(256)
void k_agg(const float* __restrict__ h, const int* __restrict__ rp,
           const int2* __restrict__ pairs, const float* __restrict__ dinv,
           const float* __restrict__ bias, const float* __restrict__ a2p,
           float* __restrict__ out)
{
  int wave = threadIdx.x >> 6;
  int lane = threadIdx.x & 63;
  int node = blockIdx.x*4 + wave;
  if (node >= NN) return;
  const float2* h2 = (const float2*)h;
  float2* o2 = (float2*)out;
  int beg = rp[node], end = rp[node+1];
  float di = dinv[node];
  float2 self = h2[(size_t)node*64 + lane];
  float2 b = ((const float2*)bias)[lane];
  float a2 = 1.f;
  if constexpr (PRELU) a2 = *a2p;
  float sc = di*di;
  float ax = sc*self.x + b.x, ay = sc*self.y + b.y;
  int e = beg;
  for (; e + 4 <= end; e += 4) {
    int2 p0 = pairs[e], p1 = pairs[e+1], p2 = pairs[e+2], p3 = pairs[e+3];
    float2 g0 = h2[(size_t)p0.x*64 + lane];
    float2 g1 = h2[(size_t)p1.x*64 + lane];
    float2 g2 = h2[(size_t)p2.x*64 + lane];
    float2 g3 = h2[(size_t)p3.x*64 + lane];
    float c0 = __int_as_float(p0.y), c1 = __int_as_float(p1.y);
    float c2 = __int_as_float(p2.y), c3 = __int_as_float(p3.y);
    ax += c0*g0.x + c1*g1.x + c2*g2.x + c3*g3.x;
    ay += c0*g0.y + c1*g1.y + c2*g2.y + c3*g3.y;
  }
  if (e + 2 <= end) {
    int2 p0 = pairs[e], p1 = pairs[e+1];
    float2 g0 = h2[(size_t)p0.x*64 + lane];
    float2 g1 = h2[(size_t)p1.x*64 + lane];
    float c0 = __int_as_float(p0.y), c1 = __int_as_float(p1.y);
    ax += c0*g0.x + c1*g1.x;
    ay += c0*g0.y + c1*g1.y;
    e += 2;
  }
  if (e < end) {
    int2 p0 = pairs[e];
    float2 g0 = h2[(size_t)p0.x*64 + lane];
    float c0 = __int_as_float(p0.y);
    ax += c0*g0.x; ay += c0*g0.y;
  }
  if constexpr (PRELU) {
    ax = (ax >= 0.f) ? ax : a2*ax;
    ay = (ay >= 0.f) ? ay : a2*ay;
  }
  o2[(size_t)node*64 + lane] = make_float2(ax, ay);
}

// ---------------- launch ----------------

extern "C" void kernel_launch(void* const* d_in, const int* in_sizes, int n_in,
                              void* d_out, int out_size, void* d_ws, size_t ws_size,
                              hipStream_t stream) {
  const float* x     = (const float*)d_in[0];
  const int*   ei    = (const int*)  d_in[1];
  const float* a1    = (const float*)d_in[2];
  const float* gamma = (const float*)d_in[3];
  const float* beta  = (const float*)d_in[4];
  const float* W1    = (const float*)d_in[5];
  const float* b1    = (const float*)d_in[6];
  const float* a2    = (const float*)d_in[7];
  const float* W2    = (const float*)d_in[8];
  const float* b2    = (const float*)d_in[9];
  float* out = (float*)d_out;

  char* w = (char*)d_ws;
  auto alloc = [&](size_t bytes) { char* p = w; w += (bytes + 255) & ~(size_t)255; return p; };
  float* hbuf  = (float*)alloc((size_t)NN*DD*4);   // 102.4 MB
  float* dinv  = (float*)alloc((size_t)NN*4);
  int*   cnt   = (int*)  alloc((size_t)NN*4);
  int*   rp    = (int*)  alloc((size_t)(NN+1)*4);
  int*   cur   = (int*)  alloc((size_t)NN*4);
  int2*  pairs = (int2*) alloc((size_t)NE*8);
  int*   bsums = (int*)  alloc(256*4);
  float* ssum  = (float*)alloc(128*4);
  float* ssq   = (float*)alloc(128*4);
  float* sarr  = (float*)alloc(128*4);
  float* tarr  = (float*)alloc(128*4);
  float* tw1   = (float*)alloc(128*4);
  u16*   w1h   = (u16*)  alloc(128*128*2);
  u16*   w1l   = (u16*)  alloc(128*128*2);
  u16*   w2h   = (u16*)  alloc(128*128*2);
  u16*   w2l   = (u16*)  alloc(128*128*2);

  const int nblkN = (NN + 255)/256;
  const int nblkE = (NE + 255)/256;

  k_zero  <<<nblkN, 256, 0, stream>>>(cnt, ssum, ssq);
  k_count <<<nblkE, 256, 0, stream>>>(ei, cnt);
  k_stats <<<1024,  256, 0, stream>>>(x, a1, ssum, ssq);
  k_bn_tw1<<<1,     128, 0, stream>>>(ssum, ssq, gamma, beta, W1, sarr, tarr, tw1);
  k_wprep <<<64,    256, 0, stream>>>(W2, nullptr, w2h, w2l);
  k_wprep <<<64,    256, 0, stream>>>(W1, sarr,    w1h, w1l);
  k_scan1 <<<196,   256, 0, stream>>>(cnt, rp, bsums);
  k_scan2 <<<1,     256, 0, stream>>>(bsums, 196);
  k_scan3 <<<nblkN, 256, 0, stream>>>(rp, bsums, cur, cnt, dinv);
  k_fill  <<<nblkE, 256, 0, stream>>>(ei, dinv, cur, pairs);

  k_gemm<true,  true ><<<GT, 256, 0, stream>>>(x,   w1h, w1l, hbuf, tw1, a1);
  k_agg <true >        <<<NN/4, 256, 0, stream>>>(hbuf, rp, pairs, dinv, b1, a2, out);
  k_gemm<false, false><<<GT, 256, 0, stream>>>(out, w2h, w2l, hbuf, nullptr, nullptr);
  k_agg <false>        <<<NN/4, 256, 0, stream>>>(hbuf, rp, pairs, dinv, b2, nullptr, out);
}

// Round 3
// 511.058 us; speedup vs baseline: 1.3252x; 1.0049x over previous
//
#include <hip/hip_runtime.h>

#define NN 200000
#define NE 600000
#define DD 128
#define GT 1563   // ceil(NN/128) gemm row tiles

constexpr float BN_EPS = 1e-5f;

typedef unsigned short u16;
typedef short bf16x8 __attribute__((ext_vector_type(8)));
typedef float f32x4  __attribute__((ext_vector_type(4)));

// ---------------- init / degree / stats ----------------

__global__ void k_zero(int* __restrict__ cnt, float* __restrict__ ssum, float* __restrict__ ssq) {
  int i = blockIdx.x*256 + threadIdx.x;
  if (i < NN) cnt[i] = 0;
  if (i < DD) { ssum[i] = 0.f; ssq[i] = 0.f; }
}

__global__ void k_count(const int* __restrict__ ei, int* __restrict__ cnt) {
  int e = blockIdx.x*256 + threadIdx.x;
  if (e < NE) atomicAdd(&cnt[ei[NE + e]], 1);
}

// column sums of prelu(x, a1): ssum[c], ssq[c]
// float4 per lane (16B), 8 row-groups/block, LDS reduce, 1 atomic/col/block.
__global__ void k_stats(const float* __restrict__ x, const float* __restrict__ a1p,
                        float* __restrict__ ssum, float* __restrict__ ssq) {
  __shared__ float s1[8][128], s2[8][128];
  const int c4 = (threadIdx.x & 31) * 4;
  const int rg = threadIdx.x >> 5;
  float a1 = *a1p;
  float acc1[4] = {0.f,0.f,0.f,0.f}, acc2[4] = {0.f,0.f,0.f,0.f};
  const int stride = gridDim.x * 8;
  for (int r = blockIdx.x*8 + rg; r < NN; r += stride) {
    float4 v = *(const float4*)(x + (size_t)r*DD + c4);
    float vv[4] = {v.x, v.y, v.z, v.w};
    #pragma unroll
    for (int i = 0; i < 4; ++i) {
      float u = vv[i];
      u = (u >= 0.f) ? u : a1*u;
      acc1[i] += u; acc2[i] += u*u;
    }
  }
  *(float4*)&s1[rg][c4] = make_float4(acc1[0], acc1[1], acc1[2], acc1[3]);
  *(float4*)&s2[rg][c4] = make_float4(acc2[0], acc2[1], acc2[2], acc2[3]);
  __syncthreads();
  if (threadIdx.x < 128) {
    int col = threadIdx.x;
    float t1 = 0.f, t2 = 0.f;
    #pragma unroll
    for (int g = 0; g < 8; ++g) { t1 += s1[g][col]; t2 += s2[g][col]; }
    atomicAdd(&ssum[col], t1);
    atomicAdd(&ssq [col], t2);
  }
}

// BN params s,t and tw1[j] = sum_k t[k] * W1[k,j]   (single block, 128 threads)
__global__ void k_bn_tw1(const float* __restrict__ ssum, const float* __restrict__ ssq,
                         const float* __restrict__ gamma, const float* __restrict__ beta,
                         const float* __restrict__ W1,
                         float* __restrict__ sarr, float* __restrict__ tarr,
                         float* __restrict__ tw1) {
  __shared__ float ts[128];
  int j = threadIdx.x;
  float mean = ssum[j] * (1.f/NN);
  float var  = ssq[j] * (1.f/NN) - mean*mean;
  float s = gamma[j] * rsqrtf(var + BN_EPS);
  float t = beta[j] - mean*s;
  sarr[j] = s; tarr[j] = t; ts[j] = t;
  __syncthreads();
  float acc = 0.f;
  #pragma unroll 8
  for (int k = 0; k < 128; ++k) acc += ts[k] * W1[k*DD + j];
  tw1[j] = acc;
}

// W prep: Wt[j][k] = (s ? s[k] : 1) * W[k][j], split into bf16 hi/lo (truncation).
// 16384 elements, grid 64 x 256.
__global__ void k_wprep(const float* __restrict__ W, const float* __restrict__ s,
                        u16* __restrict__ hi, u16* __restrict__ lo) {
  int idx = blockIdx.x*256 + threadIdx.x;
  int j = idx >> 7, k = idx & 127;
  float v = W[(size_t)k*DD + j];
  if (s) v *= s[k];
  unsigned hb = __float_as_uint(v) & 0xffff0000u;
  float r = v - __uint_as_float(hb);           // exact residual
  hi[idx] = (u16)(hb >> 16);
  lo[idx] = (u16)(__float_as_uint(r) >> 16);
}

// ---------------- exclusive scan (3 pass) ----------------

__global__ void k_scan1(const int* __restrict__ cnt, int* __restrict__ rp, int* __restrict__ bsums) {
  __shared__ int sm[256];
  int tid = threadIdx.x;
  int base = blockIdx.x*1024 + tid*4;
  int4 v = make_int4(0,0,0,0);
  if (base + 3 < NN) v = *(const int4*)(cnt + base);
  else {
    if (base   < NN) v.x = cnt[base];
    if (base+1 < NN) v.y = cnt[base+1];
    if (base+2 < NN) v.z = cnt[base+2];
    if (base+3 < NN) v.w = cnt[base+3];
  }
  int p1 = v.x, p2 = p1 + v.y, p3 = p2 + v.z, tsum = p3 + v.w;
  sm[tid] = tsum; __syncthreads();
  for (int off = 1; off < 256; off <<= 1) {
    int t = (tid >= off) ? sm[tid - off] : 0; __syncthreads();
    sm[tid] += t; __syncthreads();
  }
  int inc = sm[tid];
  int excl = inc - tsum;
  if (base   < NN) rp[base]   = excl;
  if (base+1 < NN) rp[base+1] = excl + p1;
  if (base+2 < NN) rp[base+2] = excl + p2;
  if (base+3 < NN) rp[base+3] = excl + p3;
  if (tid == 255) bsums[blockIdx.x] = inc;
}

__global__ void k_scan2(int* __restrict__ bsums, int nb) {
  __shared__ int sm[256];
  int tid = threadIdx.x;
  int v = (tid < nb) ? bsums[tid] : 0;
  sm[tid] = v; __syncthreads();
  for (int off = 1; off < 256; off <<= 1) {
    int t = (tid >= off) ? sm[tid - off] : 0; __syncthreads();
    sm[tid] += t; __syncthreads();
  }
  if (tid < nb) bsums[tid] = sm[tid] - v;   // exclusive
}

// fused: finalize row pointers + cur + dinv
__global__ void k_scan3(int* __restrict__ rp, const int* __restrict__ bsums,
                        int* __restrict__ cur, const int* __restrict__ cnt,
                        float* __restrict__ dinv) {
  int i = blockIdx.x*256 + threadIdx.x;
  if (i < NN) {
    int val = rp[i] + bsums[i >> 10];
    rp[i] = val; cur[i] = val;
    dinv[i] = rsqrtf((float)(cnt[i] + 1));
  }
  if (i == 0) rp[NN] = NE;
}

__global__ void k_fill(const int* __restrict__ ei, const float* __restrict__ dinv,
                       int* __restrict__ cur, int2* __restrict__ pairs) {
  int e = blockIdx.x*256 + threadIdx.x;
  if (e < NE) {
    int s = ei[e], d = ei[NE + e];
    int pos = atomicAdd(&cur[d], 1);
    float cf = dinv[s] * dinv[d];
    pairs[pos] = make_int2(s, __float_as_int(cf));
  }
}

// ---------------- GEMM: C[N,128] = prelu(A)[N,128] @ W'[128,128] (+ row add) ----------------
// MFMA bf16x3 split-precision: A = Ah+Al, W' = Wh+Wl (pre-split, transposed, BN scale
// folded into W1). acc += Ah*Wh + Ah*Wl + Al*Wh  -> ~fp32 accuracy at MFMA rate.

template<bool FUSE, bool ADDROW>
__global__ __launch_bounds__(256)
void k_gemm(const float* __restrict__ A,
            const u16* __restrict__ wt_hi, const u16* __restrict__ wt_lo,
            float* __restrict__ C,
            const float* __restrict__ tw1, const float* __restrict__ a1p)
{
  __shared__ u16 Bh[128][136];
  __shared__ u16 Bl[128][136];
  const int tid = threadIdx.x;

  // stage Wt hi/lo: 2048 16B chunks each, 8 per thread
  #pragma unroll
  for (int i = 0; i < 8; ++i) {
    int c = tid + i*256;
    int row = c >> 4, slot = c & 15;
    *(uint4*)&Bh[row][slot*8] = ((const uint4*)wt_hi)[c];
    *(uint4*)&Bl[row][slot*8] = ((const uint4*)wt_lo)[c];
  }

  float a1v = 0.f;
  if constexpr (FUSE) a1v = *a1p;

  const int lane = tid & 63;
  const int wv   = tid >> 6;            // wave 0..3
  const int lr   = lane & 15;           // A row within strip / C col within tile
  const int lk   = lane >> 4;           // k sub-block 0..3
  const int r0   = blockIdx.x*128 + wv*32;

  f32x4 acc[2][8];
  #pragma unroll
  for (int s = 0; s < 2; ++s)
    #pragma unroll
    for (int j = 0; j < 8; ++j) acc[s][j] = (f32x4){0.f,0.f,0.f,0.f};

  __syncthreads();

  #pragma unroll
  for (int kc = 0; kc < 4; ++kc) {
    bf16x8 ah[2], al[2];
    #pragma unroll
    for (int s = 0; s < 2; ++s) {
      int r = r0 + s*16 + lr; if (r >= NN) r = NN-1;
      const float* ap = A + (size_t)r*DD + kc*32 + lk*8;
      float4 v0 = *(const float4*)ap;
      float4 v1 = *(const float4*)(ap + 4);
      float vv[8] = {v0.x,v0.y,v0.z,v0.w,v1.x,v1.y,v1.z,v1.w};
      #pragma unroll
      for (int e = 0; e < 8; ++e) {
        float v = vv[e];
        if constexpr (FUSE) v = (v >= 0.f) ? v : a1v*v;
        unsigned hb = __float_as_uint(v) & 0xffff0000u;
        float rres = v - __uint_as_float(hb);    // exact
        ah[s][e] = (short)(hb >> 16);
        al[s][e] = (short)(__float_as_uint(rres) >> 16);
      }
    }
    #pragma unroll
    for (int j = 0; j < 8; ++j) {
      int wrow = j*16 + lr;
      bf16x8 bh = *(const bf16x8*)&Bh[wrow][kc*32 + lk*8];
      bf16x8 bl = *(const bf16x8*)&Bl[wrow][kc*32 + lk*8];
      #pragma unroll
      for (int s = 0; s < 2; ++s) {
        acc[s][j] = __builtin_amdgcn_mfma_f32_16x16x32_bf16(ah[s], bh, acc[s][j], 0, 0, 0);
        acc[s][j] = __builtin_amdgcn_mfma_f32_16x16x32_bf16(ah[s], bl, acc[s][j], 0, 0, 0);
        acc[s][j] = __builtin_amdgcn_mfma_f32_16x16x32_bf16(al[s], bh, acc[s][j], 0, 0, 0);
      }
    }
  }

  float tw[8];
  #pragma unroll
  for (int j = 0; j < 8; ++j) tw[j] = 0.f;
  if constexpr (ADDROW) {
    #pragma unroll
    for (int j = 0; j < 8; ++j) tw[j] = tw1[j*16 + lr];
  }

  // C/D layout (m89): col = lane&15, row = (lane>>4)*4 + reg
  #pragma unroll
  for (int s = 0; s < 2; ++s) {
    #pragma unroll
    for (int g = 0; g < 4; ++g) {
      int row = r0 + s*16 + lk*4 + g;
      if (row < NN) {
        float* cp = C + (size_t)row*DD + lr;
        #pragma unroll
        for (int j = 0; j < 8; ++j) cp[j*16] = acc[s][j][g] + tw[j];
      }
    }
  }
}

// ---------------- aggregation: 8 nodes per wave, interleaved gathers ----------------
// Latency-bound fix: 8 independent pair->gather chains in flight per wave.
// dinv eliminated: dinv[n]^2 = 1/(rp[n+1]-rp[n]+1). Self rows + output are
// 4KB contiguous per wave (8 consecutive rows). NN % 8 == 0.

template<bool PRELU>
__global__ __launch_bounds__(256)
void k_agg(const float* __restrict__ h, const int* __restrict__ rp,
           const int2* __restrict__ pairs,
           const float* __restrict__ bias, const float* __restrict__ a2p,
           float* __restrict__ out)
{
  const int wave = threadIdx.x >> 6;
  const int lane = threadIdx.x & 63;
  const int nb = (blockIdx.x*4 + wave) * 8;
  if (nb >= NN) return;
  const float2* h2 = (const float2*)h;
  float2* o2 = (float2*)out;

  int rv = 0;
  if (lane < 9) rv = rp[nb + lane];
  int beg[8], cnt8[8];
  #pragma unroll
  for (int i = 0; i < 8; ++i) {
    int b0 = __builtin_amdgcn_readfirstlane(__shfl(rv, i));
    int b1 = __builtin_amdgcn_readfirstlane(__shfl(rv, i+1));
    beg[i] = b0; cnt8[i] = b1 - b0;
  }

  float2 b = ((const float2*)bias)[lane];
  float a2 = 1.f;
  if constexpr (PRELU) a2 = *a2p;

  float2 acc[8];
  #pragma unroll
  for (int i = 0; i < 8; ++i) {
    float2 self = h2[(size_t)(nb+i)*64 + lane];
    float sc = 1.f / (float)(cnt8[i] + 1);     // dinv^2 exactly
    acc[i].x = sc*self.x + b.x;
    acc[i].y = sc*self.y + b.y;
  }

  int maxc = 0;
  #pragma unroll
  for (int i = 0; i < 8; ++i) maxc = max(maxc, cnt8[i]);

  for (int c = 0; c < maxc; ++c) {
    int2 p[8];
    #pragma unroll
    for (int i = 0; i < 8; ++i)
      if (c < cnt8[i]) p[i] = pairs[beg[i] + c];
    #pragma unroll
    for (int i = 0; i < 8; ++i)
      if (c < cnt8[i]) {
        float2 g = h2[(size_t)p[i].x*64 + lane];
        float cf = __int_as_float(p[i].y);
        acc[i].x += cf*g.x; acc[i].y += cf*g.y;
      }
  }

  #pragma unroll
  for (int i = 0; i < 8; ++i) {
    float ax = acc[i].x, ay = acc[i].y;
    if constexpr (PRELU) {
      ax = (ax >= 0.f) ? ax : a2*ax;
      ay = (ay >= 0.f) ? ay : a2*ay;
    }
    o2[(size_t)(nb+i)*64 + lane] = make_float2(ax, ay);
  }
}

// ---------------- launch ----------------

extern "C" void kernel_launch(void* const* d_in, const int* in_sizes, int n_in,
                              void* d_out, int out_size, void* d_ws, size_t ws_size,
                              hipStream_t stream) {
  const float* x     = (const float*)d_in[0];
  const int*   ei    = (const int*)  d_in[1];
  const float* a1    = (const float*)d_in[2];
  const float* gamma = (const float*)d_in[3];
  const float* beta  = (const float*)d_in[4];
  const float* W1    = (const float*)d_in[5];
  const float* b1    = (const float*)d_in[6];
  const float* a2    = (const float*)d_in[7];
  const float* W2    = (const float*)d_in[8];
  const float* b2    = (const float*)d_in[9];
  float* out = (float*)d_out;

  char* w = (char*)d_ws;
  auto alloc = [&](size_t bytes) { char* p = w; w += (bytes + 255) & ~(size_t)255; return p; };
  float* hbuf  = (float*)alloc((size_t)NN*DD*4);   // 102.4 MB
  float* dinv  = (float*)alloc((size_t)NN*4);
  int*   cnt   = (int*)  alloc((size_t)NN*4);
  int*   rp    = (int*)  alloc((size_t)(NN+1)*4);
  int*   cur   = (int*)  alloc((size_t)NN*4);
  int2*  pairs = (int2*) alloc((size_t)NE*8);
  int*   bsums = (int*)  alloc(256*4);
  float* ssum  = (float*)alloc(128*4);
  float* ssq   = (float*)alloc(128*4);
  float* sarr  = (float*)alloc(128*4);
  float* tarr  = (float*)alloc(128*4);
  float* tw1   = (float*)alloc(128*4);
  u16*   w1h   = (u16*)  alloc(128*128*2);
  u16*   w1l   = (u16*)  alloc(128*128*2);
  u16*   w2h   = (u16*)  alloc(128*128*2);
  u16*   w2l   = (u16*)  alloc(128*128*2);

  const int nblkN = (NN + 255)/256;
  const int nblkE = (NE + 255)/256;
  const int nblkA = NN/32;   // 8 nodes/wave * 4 waves/block

  k_zero  <<<nblkN, 256, 0, stream>>>(cnt, ssum, ssq);
  k_count <<<nblkE, 256, 0, stream>>>(ei, cnt);
  k_stats <<<1024,  256, 0, stream>>>(x, a1, ssum, ssq);
  k_bn_tw1<<<1,     128, 0, stream>>>(ssum, ssq, gamma, beta, W1, sarr, tarr, tw1);
  k_wprep <<<64,    256, 0, stream>>>(W2, nullptr, w2h, w2l);
  k_wprep <<<64,    256, 0, stream>>>(W1, sarr,    w1h, w1l);
  k_scan1 <<<196,   256, 0, stream>>>(cnt, rp, bsums);
  k_scan2 <<<1,     256, 0, stream>>>(bsums, 196);
  k_scan3 <<<nblkN, 256, 0, stream>>>(rp, bsums, cur, cnt, dinv);
  k_fill  <<<nblkE, 256, 0, stream>>>(ei, dinv, cur, pairs);

  k_gemm<true,  true ><<<GT, 256, 0, stream>>>(x,   w1h, w1l, hbuf, tw1, a1);
  k_agg <true >        <<<nblkA, 256, 0, stream>>>(hbuf, rp, pairs, b1, a2, out);
  k_gemm<false, false><<<GT, 256, 0, stream>>>(out, w2h, w2l, hbuf, nullptr, nullptr);
  k_agg <false>        <<<nblkA, 256, 0, stream>>>(hbuf, rp, pairs, b2, nullptr, out);
}